// Round 8
// baseline (417.134 us; speedup 1.0000x reference)
//
#include <hip/hip_runtime.h>
#include <hip/hip_bf16.h>

#define N_NODES   100000
#define N_EDGES   1600000
#define N_GRAPHS  64
#define FDIM      128
#define N_LABELS  20
#define NBK       64                  // nodes per dst-bucket
#define P_BKT     1563                // ceil(N_NODES/NBK)
#define NCHUNKS   512                 // edge chunks (power of 2)
#define NCHUNKS_LOG 9
#define CHUNK     3125                // N_EDGES / NCHUNKS
#define SCAN_M    (P_BKT * NCHUNKS)   // 800256
#define SB1_BLOCKS 3126               // ceil(SCAN_M/256)
#define SB_BLOCKS 391                 // ceil(N_NODES/256)
#define PCHUNKS   32                  // pooling chunks per graph
#define APAD      17                  // uint4 pitch for A/R LDS rows (16+1)

typedef __bf16 bf16x8 __attribute__((ext_vector_type(8)));
typedef float  f32x4  __attribute__((ext_vector_type(4)));
union frag_u { uint4 u; bf16x8 b; };

__device__ __forceinline__ unsigned bfr(float v) {   // fp32 -> bf16 (RTNE-ish)
  unsigned b = __float_as_uint(v);
  return (b + 0x7fffu + ((b >> 16) & 1u)) >> 16;
}

// ---------------- prep: cvt_emb + cvt_w + find_starts + init, one launch ----
__global__ __launch_bounds__(256) void prep_kernel(
    const float* __restrict__ emb, unsigned short* __restrict__ embbf,
    const float* __restrict__ w1rel, const float* __restrict__ w1rt,
    const float* __restrict__ w2rel, const float* __restrict__ w2rt,
    unsigned short* __restrict__ wt1, unsigned short* __restrict__ wt2,
    const int* __restrict__ batch, int* __restrict__ start,
    float* __restrict__ pool, float* __restrict__ zrow,
    int* __restrict__ csr, int* __restrict__ csr2,
    int* __restrict__ offsets) {
  int b = blockIdx.x;
  int tid = threadIdx.x;
  if (b < 6250) {                       // ---- emb -> bf16 (quad id)
    int i = b * 256 + tid;
    float4 v = ((const float4*)emb)[i];
    uint2 o;
    o.x = bfr(v.x) | (bfr(v.y) << 16);
    o.y = bfr(v.z) | (bfr(v.w) << 16);
    ((uint2*)embbf)[i] = o;
  } else if (b < 6506) {                // ---- W -> bf16 transposed
    int gid = (b - 6250) * 256 + tid;   // 65536
    int l = gid >> 15;
    int rem = gid & 32767;
    int c = rem >> 8, k = rem & 255;
    const float* w = l ? ((k < 128) ? w2rel : w2rt) : ((k < 128) ? w1rel : w1rt);
    float v = w[(size_t)(k & 127) * FDIM + c];
    (l ? wt2 : wt1)[c * 256 + k] = (unsigned short)bfr(v);
  } else if (b < 6897) {                // ---- find_starts (batch sorted)
    int i = (b - 6506) * 256 + tid;
    if (i >= N_NODES) return;
    int bb = batch[i];
    int bp = (i == 0) ? -1 : batch[i - 1];
    for (int g = bp + 1; g <= bb; ++g) start[g] = i;
    if (i == N_NODES - 1) {
      for (int g = bb + 1; g <= N_GRAPHS; ++g) start[g] = N_NODES;
    }
  } else {                              // ---- init
    int i = (b - 6897) * 256 + tid;
    if (i < N_GRAPHS * 256) pool[i] = 0.f;
    if (i < FDIM) zrow[i] = 0.f;
    if (i < 32) { csr[N_EDGES + i] = 0; csr2[N_EDGES + i] = 0; }
    if (i == 32) offsets[N_NODES] = N_EDGES;
  }
}

// ---------------- A1: per-chunk bucket histogram ----------------
__global__ __launch_bounds__(256) void histA_kernel(
    const int* __restrict__ ei, int* __restrict__ cntmat) {
  __shared__ int hist[P_BKT];
  int tid = threadIdx.x;
  for (int i = tid; i < P_BKT; i += 256) hist[i] = 0;
  __syncthreads();
  int base = blockIdx.x * CHUNK;
  for (int i = tid; i < CHUNK; i += 256) {
    int d = ei[N_EDGES + base + i];
    atomicAdd(&hist[d >> 6], 1);
  }
  __syncthreads();
  for (int p = tid; p < P_BKT; p += 256)
    cntmat[p * NCHUNKS + blockIdx.x] = hist[p];
}

// ---------------- A2: 3-level exclusive scan over cntmat (bucket-major) -----
__global__ __launch_bounds__(256) void scanB1_kernel(
    const int* __restrict__ v, int* __restrict__ part,
    int* __restrict__ bsum) {
  __shared__ int s[256];
  int tid = threadIdx.x;
  int i = blockIdx.x * 256 + tid;
  int val = (i < SCAN_M) ? v[i] : 0;
  s[tid] = val;
  __syncthreads();
  for (int off = 1; off < 256; off <<= 1) {
    int t = (tid >= off) ? s[tid - off] : 0;
    __syncthreads();
    s[tid] += t;
    __syncthreads();
  }
  if (i < SCAN_M) part[i] = s[tid] - val;
  if (tid == 255) bsum[blockIdx.x] = s[255];
}

// 512 threads x 8 elements = 4096 slots >= SB1_BLOCKS
__global__ __launch_bounds__(512) void scanB2_kernel(int* __restrict__ bsum) {
  __shared__ int s[512];
  int tid = threadIdx.x;
  int v[8];
  int tot = 0;
#pragma unroll
  for (int j = 0; j < 8; ++j) {
    int idx = tid * 8 + j;
    v[j] = (idx < SB1_BLOCKS) ? bsum[idx] : 0;
    tot += v[j];
  }
  s[tid] = tot;
  __syncthreads();
  for (int off = 1; off < 512; off <<= 1) {
    int t = (tid >= off) ? s[tid - off] : 0;
    __syncthreads();
    s[tid] += t;
    __syncthreads();
  }
  int run = s[tid] - tot;
#pragma unroll
  for (int j = 0; j < 8; ++j) {
    int idx = tid * 8 + j;
    int val = v[j];
    if (idx < SB1_BLOCKS) bsum[idx] = run;
    run += val;
  }
}

__global__ __launch_bounds__(256) void scanB3_kernel(
    int* __restrict__ part, const int* __restrict__ bsum,
    int* __restrict__ bstart) {
  int i = blockIdx.x * 256 + threadIdx.x;
  if (i < SCAN_M) {
    int o = part[i] + bsum[blockIdx.x];
    part[i] = o;
    if ((i & (NCHUNKS - 1)) == 0) bstart[i >> NCHUNKS_LOG] = o;
  }
  if (blockIdx.x == 0 && threadIdx.x == 0) bstart[P_BKT] = N_EDGES;
}

// ---------------- A3: scatter edges grouped by bucket (packed src<<6|ldst) --
__global__ __launch_bounds__(256) void scatA_kernel(
    const int* __restrict__ ei, const int* __restrict__ S,
    int* __restrict__ ebuf) {
  __shared__ int rc[P_BKT];
  int tid = threadIdx.x;
  for (int p = tid; p < P_BKT; p += 256)
    rc[p] = S[p * NCHUNKS + blockIdx.x];
  __syncthreads();
  int base = blockIdx.x * CHUNK;
  for (int i = tid; i < CHUNK; i += 256) {
    int s0 = ei[base + i];
    int d0 = ei[N_EDGES + base + i];
    int pos = atomicAdd(&rc[d0 >> 6], 1);
    ebuf[pos] = (s0 << 6) | (d0 & 63);
  }
}

// ---------------- A4: per-bucket CSR build (single-writer csr window) -------
__global__ __launch_bounds__(256) void fill2_kernel(
    const int* __restrict__ ebuf, const int* __restrict__ bstart,
    const int* __restrict__ x, int* __restrict__ offsets,
    int* __restrict__ csr, int* __restrict__ csr2) {
  __shared__ int ldeg[NBK], loffs[NBK], rc2[NBK];
  int tid = threadIdx.x;
  int p = blockIdx.x;
  int beg = bstart[p], end = bstart[p + 1];
  if (tid < NBK) ldeg[tid] = 0;
  __syncthreads();
  for (int i = beg + tid; i < end; i += 256)
    atomicAdd(&ldeg[ebuf[i] & 63], 1);
  __syncthreads();
  if (tid == 0) {
    int run = 0;
    for (int r = 0; r < NBK; ++r) { loffs[r] = run; run += ldeg[r]; }
  }
  __syncthreads();
  if (tid < NBK) {
    rc2[tid] = loffs[tid];
    int gn = p * NBK + tid;
    if (gn < N_NODES) offsets[gn] = beg + loffs[tid];
  }
  __syncthreads();
  for (int i = beg + tid; i < end; i += 256) {
    int e = ebuf[i];
    int ld = e & 63;
    int src = e >> 6;
    int pos = atomicAdd(&rc2[ld], 1);
    csr[beg + pos] = src;
    csr2[beg + pos] = x[src];
  }
}

// ---------------- fused layer: h_out = relu([agg(feat)|root]@Wt^T + b) ------
// Block = 256 threads, 16 nodes. Phase 1: round-2 agg schedule (16 lanes/row,
// uint4 gathers, 8-deep). Phase 2: agg rows -> LDS A_s, root rows -> LDS R_s
// (uint4 pitch 17: b128 reads land 8 lanes per bank-quad, even). Phase 3:
// each wave computes m=16 x n=32 (nt = 2w,2w+1), k=256; B-frags direct from
// global wt (64KB, L2-hot). Fragment math identical to the verified gemm.
__global__ __launch_bounds__(256) void layer_kernel(
    const unsigned short* __restrict__ feat, const int* __restrict__ srcidx,
    const int* __restrict__ offs, const float* __restrict__ zrow,
    const unsigned short* __restrict__ rootbf, const int* __restrict__ hidx,
    const unsigned short* __restrict__ wt,      // [128 c][256 k] bf16
    const float* __restrict__ bias,
    float* __restrict__ hout_f32,               // layer-2 output
    unsigned short* __restrict__ hout_bf) {     // layer-1 output
  __shared__ uint4 A_s[16 * APAD];
  __shared__ uint4 R_s[16 * APAD];
  int tid = threadIdx.x;
  int sub = tid >> 4;
  int fq  = tid & 15;
  int node = blockIdx.x * 16 + sub;

  // issue root-row gather early (oldest in queue; waits don't stall gathers)
  int hr = hidx ? hidx[node] : node;
  uint4 rootw = ((const uint4*)rootbf)[(size_t)hr * 16 + fq];

  float4 e0 = make_float4(0.f, 0.f, 0.f, 0.f);
  float4 e1 = make_float4(0.f, 0.f, 0.f, 0.f);
  float4 o0 = make_float4(0.f, 0.f, 0.f, 0.f);
  float4 o1 = make_float4(0.f, 0.f, 0.f, 0.f);
  int s = offs[node], e = offs[node + 1];

  const uint4* __restrict__ fb = (const uint4*)feat;   // 16 uint4 per row
  const uint4* __restrict__ zb = (const uint4*)zrow;   // 256 B of zero bits

  int p = s;
  for (; p + 8 <= e; p += 8) {
    const uint4* rp[8];
#pragma unroll
    for (int u = 0; u < 8; ++u)
      rp[u] = fb + (size_t)srcidx[p + u] * 16;
    uint4 w[8];
#pragma unroll
    for (int u = 0; u < 8; ++u) w[u] = rp[u][fq];
#pragma unroll
    for (int u = 0; u < 8; ++u) {
      float4& A = (u & 1) ? o0 : e0;
      float4& B = (u & 1) ? o1 : e1;
      A.x += __uint_as_float(w[u].x << 16);
      A.y += __uint_as_float(w[u].x & 0xffff0000u);
      A.z += __uint_as_float(w[u].y << 16);
      A.w += __uint_as_float(w[u].y & 0xffff0000u);
      B.x += __uint_as_float(w[u].z << 16);
      B.y += __uint_as_float(w[u].z & 0xffff0000u);
      B.z += __uint_as_float(w[u].w << 16);
      B.w += __uint_as_float(w[u].w & 0xffff0000u);
    }
  }
  if (p < e) {
    const uint4* rp[8];
#pragma unroll
    for (int u = 0; u < 8; ++u) {
      int iu = srcidx[p + u];
      rp[u] = (p + u < e) ? (fb + (size_t)iu * 16) : zb;
    }
    uint4 w[8];
#pragma unroll
    for (int u = 0; u < 8; ++u) w[u] = rp[u][fq];
#pragma unroll
    for (int u = 0; u < 8; ++u) {
      float4& A = (u & 1) ? o0 : e0;
      float4& B = (u & 1) ? o1 : e1;
      A.x += __uint_as_float(w[u].x << 16);
      A.y += __uint_as_float(w[u].x & 0xffff0000u);
      A.z += __uint_as_float(w[u].y << 16);
      A.w += __uint_as_float(w[u].y & 0xffff0000u);
      B.x += __uint_as_float(w[u].z << 16);
      B.y += __uint_as_float(w[u].z & 0xffff0000u);
      B.z += __uint_as_float(w[u].w << 16);
      B.w += __uint_as_float(w[u].w & 0xffff0000u);
    }
  }
  float f0 = e0.x + o0.x, f1 = e0.y + o0.y, f2 = e0.z + o0.z, f3 = e0.w + o0.w;
  float f4 = e1.x + o1.x, f5 = e1.y + o1.y, f6 = e1.z + o1.z, f7 = e1.w + o1.w;
  uint4 o;
  o.x = bfr(f0) | (bfr(f1) << 16);
  o.y = bfr(f2) | (bfr(f3) << 16);
  o.z = bfr(f4) | (bfr(f5) << 16);
  o.w = bfr(f6) | (bfr(f7) << 16);
  A_s[sub * APAD + fq] = o;
  R_s[sub * APAD + fq] = rootw;
  __syncthreads();

  // ---- gemm phase: wave wv handles n-tiles {2wv, 2wv+1} over all 16 nodes
  int lane = tid & 63;
  int wv = tid >> 6;
  int lo = lane & 15, hi = lane >> 4;

  f32x4 acc[2];
#pragma unroll
  for (int j = 0; j < 2; ++j) {
    float b = bias[(wv * 2 + j) * 16 + lo];
    acc[j][0] = b; acc[j][1] = b; acc[j][2] = b; acc[j][3] = b;
  }
#pragma unroll
  for (int t = 0; t < 8; ++t) {     // t<4: agg (k=t*32), t>=4: root (k=128+..)
    frag_u a;
    a.u = (t < 4) ? A_s[lo * APAD + t * 4 + hi]
                  : R_s[lo * APAD + (t - 4) * 4 + hi];
#pragma unroll
    for (int j = 0; j < 2; ++j) {
      int nt = wv * 2 + j;
      frag_u bfv;
      bfv.u = *(const uint4*)(wt + (size_t)(nt * 16 + lo) * 256 + t * 32 + hi * 8);
      acc[j] = __builtin_amdgcn_mfma_f32_16x16x32_bf16(a.b, bfv.b, acc[j], 0, 0, 0);
    }
  }

  // epilogue: D row = hi*4 + r (node), col = nt*16 + lo
  int nodeBase = blockIdx.x * 16;
#pragma unroll
  for (int j = 0; j < 2; ++j) {
    int nt = wv * 2 + j;
#pragma unroll
    for (int r = 0; r < 4; ++r) {
      int n = nodeBase + hi * 4 + r;
      if (hout_bf)
        hout_bf[(size_t)n * FDIM + nt * 16 + lo] =
            (unsigned short)bfr(fmaxf(acc[j][r], 0.f));
      else
        hout_f32[(size_t)n * FDIM + nt * 16 + lo] = fmaxf(acc[j][r], 0.f);
    }
  }
}

// ---------------- pooling: max & sum per graph ----------------
__global__ __launch_bounds__(256) void pool_kernel(
    const float* __restrict__ h2, const int* __restrict__ start,
    float* __restrict__ pool) {
  __shared__ float4 rmax[8][32];
  __shared__ float4 rsum[8][32];
  int g = blockIdx.x >> 5;
  int c = blockIdx.x & (PCHUNKS - 1);
  int tid = threadIdx.x;
  int fq = tid & 31;
  int sub = tid >> 5;
  int s = start[g], e = start[g + 1];
  int len = e - s;
  int lo = s + (int)(((long long)len * c) >> 5);
  int hi = s + (int)(((long long)len * (c + 1)) >> 5);
  float4 mx = make_float4(0.f, 0.f, 0.f, 0.f);
  float4 sm = make_float4(0.f, 0.f, 0.f, 0.f);
  for (int n = lo + sub; n < hi; n += 8) {
    float4 v = ((const float4*)(h2 + (size_t)n * FDIM))[fq];
    mx.x = fmaxf(mx.x, v.x); mx.y = fmaxf(mx.y, v.y);
    mx.z = fmaxf(mx.z, v.z); mx.w = fmaxf(mx.w, v.w);
    sm.x += v.x; sm.y += v.y; sm.z += v.z; sm.w += v.w;
  }
  rmax[sub][fq] = mx;
  rsum[sub][fq] = sm;
  __syncthreads();
  if (sub == 0) {
#pragma unroll
    for (int r = 1; r < 8; ++r) {
      float4 m2 = rmax[r][fq], s2 = rsum[r][fq];
      mx.x = fmaxf(mx.x, m2.x); mx.y = fmaxf(mx.y, m2.y);
      mx.z = fmaxf(mx.z, m2.z); mx.w = fmaxf(mx.w, m2.w);
      sm.x += s2.x; sm.y += s2.y; sm.z += s2.z; sm.w += s2.w;
    }
    unsigned int* pm = (unsigned int*)&pool[g * 256 + fq * 4];
    atomicMax(pm + 0, __float_as_uint(mx.x));
    atomicMax(pm + 1, __float_as_uint(mx.y));
    atomicMax(pm + 2, __float_as_uint(mx.z));
    atomicMax(pm + 3, __float_as_uint(mx.w));
    float* ps = &pool[g * 256 + 128 + fq * 4];
    atomicAdd(ps + 0, sm.x);
    atomicAdd(ps + 1, sm.y);
    atomicAdd(ps + 2, sm.z);
    atomicAdd(ps + 3, sm.w);
  }
}

__global__ void pool_fin_kernel(float* __restrict__ pool,
                                const int* __restrict__ start) {
  int gid = blockIdx.x * 256 + threadIdx.x;   // 8192
  int g = gid >> 7, f = gid & 127;
  int cnt = start[g + 1] - start[g];
  float c = (float)(cnt > 1 ? cnt : 1);
  pool[g * 256 + 128 + f] /= c;
}

// ---------------- MLP head ----------------
__global__ void head1_kernel(const float* __restrict__ pool,
                             const float* __restrict__ lw1,
                             const float* __restrict__ lb1,
                             float* __restrict__ t1) {
  int gid = blockIdx.x * 256 + threadIdx.x;   // 8192
  int r = gid >> 7, c = gid & 127;
  float acc = lb1[c];
  for (int k = 0; k < 256; ++k) acc += pool[r * 256 + k] * lw1[k * 128 + c];
  t1[gid] = fmaxf(acc, 0.f);
}

__global__ void head2_kernel(const float* __restrict__ t1,
                             const float* __restrict__ lw2,
                             const float* __restrict__ lb2,
                             float* __restrict__ t2) {
  int gid = blockIdx.x * 256 + threadIdx.x;   // 4096
  int r = gid >> 6, c = gid & 63;
  float acc = lb2[c];
  for (int k = 0; k < 128; ++k) acc += t1[r * 128 + k] * lw2[k * 64 + c];
  t2[gid] = fmaxf(acc, 0.f);
}

__global__ __launch_bounds__(256) void head3_kernel(
    const float* __restrict__ t2, const float* __restrict__ lw3,
    const float* __restrict__ lb3, float* __restrict__ out) {
  __shared__ float lg[N_GRAPHS * N_LABELS];
  __shared__ float col[N_LABELS];
  int tid = threadIdx.x;
  for (int o = tid; o < N_GRAPHS * N_LABELS; o += 256) {
    int r = o / N_LABELS, c = o - r * N_LABELS;
    float acc = lb3[c];
    for (int k = 0; k < 64; ++k) acc += t2[r * 64 + k] * lw3[k * N_LABELS + c];
    lg[o] = acc;
  }
  __syncthreads();
  if (tid < N_LABELS) {
    float m = -1e30f;
    for (int r = 0; r < N_GRAPHS; ++r) m = fmaxf(m, lg[r * N_LABELS + tid]);
    float s = 0.f;
    for (int r = 0; r < N_GRAPHS; ++r) s += expf(lg[r * N_LABELS + tid] - m);
    col[tid] = m + logf(s);
  }
  __syncthreads();
  for (int o = tid; o < N_GRAPHS * N_LABELS; o += 256) {
    int c = o % N_LABELS;
    out[o] = lg[o] - col[c];
  }
}

// ---------------- launch ----------------
extern "C" void kernel_launch(void* const* d_in, const int* in_sizes, int n_in,
                              void* d_out, int out_size, void* d_ws, size_t ws_size,
                              hipStream_t stream) {
  const int*   x     = (const int*)  d_in[0];
  const int*   ei    = (const int*)  d_in[1];
  const int*   batch = (const int*)  d_in[2];
  const float* emb   = (const float*)d_in[3];
  const float* w1rel = (const float*)d_in[4];
  const float* w1rt  = (const float*)d_in[5];
  const float* b1    = (const float*)d_in[6];
  const float* w2rel = (const float*)d_in[7];
  const float* w2rt  = (const float*)d_in[8];
  const float* b2    = (const float*)d_in[9];
  const float* lw1   = (const float*)d_in[10];
  const float* lb1   = (const float*)d_in[11];
  const float* lw2   = (const float*)d_in[12];
  const float* lb2   = (const float*)d_in[13];
  const float* lw3   = (const float*)d_in[14];
  const float* lb3   = (const float*)d_in[15];
  float* out = (float*)d_out;

  char* ws = (char*)d_ws;
  const size_t HB   = 51200000;    // N_NODES*FDIM*4
  const size_t CSRB = 6400128;     // (N_EDGES+32) ints
  const size_t OFFB = 400128;      // (N_NODES+1) ints, rounded
  float* hB      = (float*)(ws);
  // embbf aliases hB [0,12.8MB): dead before layer2 writes hB
  unsigned short* embbf = (unsigned short*)(ws);
  // scan buffers alias hB [13MB,20.1MB): dead before layer2 writes hB
  int*   cntmat  = (int*)  (ws + 13000000);   // SCAN_M ints = 3.2MB
  int*   S       = (int*)  (ws + 16500000);   // SCAN_M ints = 3.2MB
  int*   bsum    = (int*)  (ws + 20000000);   // SB1_BLOCKS ints = 12.5KB
  int*   ebuf    = (int*)  (ws + HB);
  int*   csr     = (int*)  (ws + 2 * HB);
  int*   csr2    = (int*)  (ws + 2 * HB + CSRB);
  int*   offsets = (int*)  (ws + 2 * HB + 2 * CSRB);
  int*   bstart  = (int*)  (ws + 2 * HB + 2 * CSRB + OFFB);            // 6,400
  float* zrow    = (float*)(ws + 2 * HB + 2 * CSRB + OFFB + 6400);     // 512
  int*   start   = (int*)  (ws + 2 * HB + 2 * CSRB + OFFB + 6912);     // 512
  float* pool    = (float*)(ws + 2 * HB + 2 * CSRB + OFFB + 7424);     // 65,536
  float* t1      = (float*)(ws + 2 * HB + 2 * CSRB + OFFB + 72960);    // 32,768
  float* t2      = (float*)(ws + 2 * HB + 2 * CSRB + OFFB + 105728);   // 16,384
  unsigned short* hbf =
      (unsigned short*)(ws + 2 * HB + 2 * CSRB + OFFB + 122112);       // 25.6 MB
  unsigned short* wt1 =
      (unsigned short*)(ws + 2 * HB + 2 * CSRB + OFFB + 122112 + 25600000);
  unsigned short* wt2 = wt1 + 128 * 256;

  prep_kernel<<<6961, 256, 0, stream>>>(emb, embbf, w1rel, w1rt, w2rel, w2rt,
                                        wt1, wt2, batch, start, pool, zrow,
                                        csr, csr2, offsets);

  histA_kernel<<<NCHUNKS, 256, 0, stream>>>(ei, cntmat);
  scanB1_kernel<<<SB1_BLOCKS, 256, 0, stream>>>(cntmat, S, bsum);
  scanB2_kernel<<<1, 512, 0, stream>>>(bsum);
  scanB3_kernel<<<SB1_BLOCKS, 256, 0, stream>>>(S, bsum, bstart);
  scatA_kernel<<<NCHUNKS, 256, 0, stream>>>(ei, S, ebuf);
  fill2_kernel<<<P_BKT, 256, 0, stream>>>(ebuf, bstart, x, offsets, csr, csr2);

  // layer 1: agg over bf16 emb rows (csr2 = x[src]); root = embbf via x
  layer_kernel<<<N_NODES / 16, 256, 0, stream>>>(
      embbf, csr2, offsets, zrow, embbf, x, wt1, b1,
      (float*)nullptr, hbf);

  // layer 2: agg over bf16 h1 rows (csr); root = hbf; fp32 out for pooling
  layer_kernel<<<N_NODES / 16, 256, 0, stream>>>(
      hbf, csr, offsets, zrow, hbf, (const int*)nullptr, wt2, b2,
      hB, (unsigned short*)nullptr);

  pool_kernel<<<N_GRAPHS * PCHUNKS, 256, 0, stream>>>(hB, start, pool);
  pool_fin_kernel<<<32, 256, 0, stream>>>(pool, start);

  head1_kernel<<<32, 256, 0, stream>>>(pool, lw1, lb1, t1);
  head2_kernel<<<16, 256, 0, stream>>>(t1, lw2, lb2, t2);
  head3_kernel<<<1, 256, 0, stream>>>(t2, lw3, lb3, out);
}

// Round 9
// 370.905 us; speedup vs baseline: 1.1246x; 1.1246x over previous
//
#include <hip/hip_runtime.h>
#include <hip/hip_bf16.h>

#define N_NODES   100000
#define N_EDGES   1600000
#define N_GRAPHS  64
#define FDIM      128
#define N_LABELS  20
#define NBK       64                  // nodes per dst-bucket
#define P_BKT     1563                // ceil(N_NODES/NBK)
#define NCHUNKS   512                 // edge chunks (power of 2)
#define NCHUNKS_LOG 9
#define CHUNK     3125                // N_EDGES / NCHUNKS
#define SCAN_M    (P_BKT * NCHUNKS)   // 800256
#define SB1_BLOCKS 3126               // ceil(SCAN_M/256)
#define SB_BLOCKS 391                 // ceil(N_NODES/256)
#define BPITCH    136                 // bf16 pitch for B half-slab (128+8)

typedef __bf16 bf16x8 __attribute__((ext_vector_type(8)));
typedef float  f32x4  __attribute__((ext_vector_type(4)));
union frag_u { uint4 u; bf16x8 b; };

__device__ __forceinline__ unsigned bfr(float v) {   // fp32 -> bf16 (RTNE-ish)
  unsigned b = __float_as_uint(v);
  return (b + 0x7fffu + ((b >> 16) & 1u)) >> 16;
}

// ---------------- prep: cvt_emb + cvt_w + find_starts + init, one launch ----
__global__ __launch_bounds__(256) void prep_kernel(
    const float* __restrict__ emb, unsigned short* __restrict__ embbf,
    const float* __restrict__ w1rel, const float* __restrict__ w1rt,
    const float* __restrict__ w2rel, const float* __restrict__ w2rt,
    unsigned short* __restrict__ wt1, unsigned short* __restrict__ wt2,
    const int* __restrict__ batch, int* __restrict__ start,
    float* __restrict__ pool, float* __restrict__ zrow,
    int* __restrict__ csr, int* __restrict__ csr2,
    int* __restrict__ offsets) {
  int b = blockIdx.x;
  int tid = threadIdx.x;
  if (b < 6250) {                       // ---- emb -> bf16 (quad id)
    int i = b * 256 + tid;
    float4 v = ((const float4*)emb)[i];
    uint2 o;
    o.x = bfr(v.x) | (bfr(v.y) << 16);
    o.y = bfr(v.z) | (bfr(v.w) << 16);
    ((uint2*)embbf)[i] = o;
  } else if (b < 6506) {                // ---- W -> bf16 transposed
    int gid = (b - 6250) * 256 + tid;   // 65536
    int l = gid >> 15;
    int rem = gid & 32767;
    int c = rem >> 8, k = rem & 255;
    const float* w = l ? ((k < 128) ? w2rel : w2rt) : ((k < 128) ? w1rel : w1rt);
    float v = w[(size_t)(k & 127) * FDIM + c];
    (l ? wt2 : wt1)[c * 256 + k] = (unsigned short)bfr(v);
  } else if (b < 6897) {                // ---- find_starts (batch sorted)
    int i = (b - 6506) * 256 + tid;
    if (i >= N_NODES) return;
    int bb = batch[i];
    int bp = (i == 0) ? -1 : batch[i - 1];
    for (int g = bp + 1; g <= bb; ++g) start[g] = i;
    if (i == N_NODES - 1) {
      for (int g = bb + 1; g <= N_GRAPHS; ++g) start[g] = N_NODES;
    }
  } else {                              // ---- init
    int i = (b - 6897) * 256 + tid;
    if (i < N_GRAPHS * 256) pool[i] = 0.f;
    if (i < FDIM) zrow[i] = 0.f;
    if (i < 32) { csr[N_EDGES + i] = 0; csr2[N_EDGES + i] = 0; }
    if (i == 32) offsets[N_NODES] = N_EDGES;
  }
}

// ---------------- A1: per-chunk bucket histogram ----------------
__global__ __launch_bounds__(256) void histA_kernel(
    const int* __restrict__ ei, int* __restrict__ cntmat) {
  __shared__ int hist[P_BKT];
  int tid = threadIdx.x;
  for (int i = tid; i < P_BKT; i += 256) hist[i] = 0;
  __syncthreads();
  int base = blockIdx.x * CHUNK;
  for (int i = tid; i < CHUNK; i += 256) {
    int d = ei[N_EDGES + base + i];
    atomicAdd(&hist[d >> 6], 1);
  }
  __syncthreads();
  for (int p = tid; p < P_BKT; p += 256)
    cntmat[p * NCHUNKS + blockIdx.x] = hist[p];
}

// ---------------- A2: 3-level exclusive scan over cntmat (bucket-major) -----
__global__ __launch_bounds__(256) void scanB1_kernel(
    const int* __restrict__ v, int* __restrict__ part,
    int* __restrict__ bsum) {
  __shared__ int s[256];
  int tid = threadIdx.x;
  int i = blockIdx.x * 256 + tid;
  int val = (i < SCAN_M) ? v[i] : 0;
  s[tid] = val;
  __syncthreads();
  for (int off = 1; off < 256; off <<= 1) {
    int t = (tid >= off) ? s[tid - off] : 0;
    __syncthreads();
    s[tid] += t;
    __syncthreads();
  }
  if (i < SCAN_M) part[i] = s[tid] - val;
  if (tid == 255) bsum[blockIdx.x] = s[255];
}

// 512 threads x 8 elements = 4096 slots >= SB1_BLOCKS
__global__ __launch_bounds__(512) void scanB2_kernel(int* __restrict__ bsum) {
  __shared__ int s[512];
  int tid = threadIdx.x;
  int v[8];
  int tot = 0;
#pragma unroll
  for (int j = 0; j < 8; ++j) {
    int idx = tid * 8 + j;
    v[j] = (idx < SB1_BLOCKS) ? bsum[idx] : 0;
    tot += v[j];
  }
  s[tid] = tot;
  __syncthreads();
  for (int off = 1; off < 512; off <<= 1) {
    int t = (tid >= off) ? s[tid - off] : 0;
    __syncthreads();
    s[tid] += t;
    __syncthreads();
  }
  int run = s[tid] - tot;
#pragma unroll
  for (int j = 0; j < 8; ++j) {
    int idx = tid * 8 + j;
    int val = v[j];
    if (idx < SB1_BLOCKS) bsum[idx] = run;
    run += val;
  }
}

__global__ __launch_bounds__(256) void scanB3_kernel(
    int* __restrict__ part, const int* __restrict__ bsum,
    int* __restrict__ bstart) {
  int i = blockIdx.x * 256 + threadIdx.x;
  if (i < SCAN_M) {
    int o = part[i] + bsum[blockIdx.x];
    part[i] = o;
    if ((i & (NCHUNKS - 1)) == 0) bstart[i >> NCHUNKS_LOG] = o;
  }
  if (blockIdx.x == 0 && threadIdx.x == 0) bstart[P_BKT] = N_EDGES;
}

// ---------------- A3: scatter edges grouped by bucket (packed src<<6|ldst) --
__global__ __launch_bounds__(256) void scatA_kernel(
    const int* __restrict__ ei, const int* __restrict__ S,
    int* __restrict__ ebuf) {
  __shared__ int rc[P_BKT];
  int tid = threadIdx.x;
  for (int p = tid; p < P_BKT; p += 256)
    rc[p] = S[p * NCHUNKS + blockIdx.x];
  __syncthreads();
  int base = blockIdx.x * CHUNK;
  for (int i = tid; i < CHUNK; i += 256) {
    int s0 = ei[base + i];
    int d0 = ei[N_EDGES + base + i];
    int pos = atomicAdd(&rc[d0 >> 6], 1);
    ebuf[pos] = (s0 << 6) | (d0 & 63);
  }
}

// ---------------- A4: per-bucket CSR build (single-writer csr window) -------
__global__ __launch_bounds__(256) void fill2_kernel(
    const int* __restrict__ ebuf, const int* __restrict__ bstart,
    const int* __restrict__ x, int* __restrict__ offsets,
    int* __restrict__ csr, int* __restrict__ csr2) {
  __shared__ int ldeg[NBK], loffs[NBK], rc2[NBK];
  int tid = threadIdx.x;
  int p = blockIdx.x;
  int beg = bstart[p], end = bstart[p + 1];
  if (tid < NBK) ldeg[tid] = 0;
  __syncthreads();
  for (int i = beg + tid; i < end; i += 256)
    atomicAdd(&ldeg[ebuf[i] & 63], 1);
  __syncthreads();
  if (tid == 0) {
    int run = 0;
    for (int r = 0; r < NBK; ++r) { loffs[r] = run; run += ldeg[r]; }
  }
  __syncthreads();
  if (tid < NBK) {
    rc2[tid] = loffs[tid];
    int gn = p * NBK + tid;
    if (gn < N_NODES) offsets[gn] = beg + loffs[tid];
  }
  __syncthreads();
  for (int i = beg + tid; i < end; i += 256) {
    int e = ebuf[i];
    int ld = e & 63;
    int src = e >> 6;
    int pos = atomicAdd(&rc2[ld], 1);
    csr[beg + pos] = src;
    csr2[beg + pos] = x[src];
  }
}

// ---------------- aggregation: aggout(bf16) = sum feat(bf16 rows) ------------
// 16 lanes per node row (uint4 = 16 B/lane), 16 nodes per 256-thread block.
// Round-2 schedule (measured floor: 56.3 us).
__global__ __launch_bounds__(256) void agg_kernel(
    const unsigned short* __restrict__ feat, const int* __restrict__ srcidx,
    const int* __restrict__ offs, const float* __restrict__ zrow,
    unsigned short* __restrict__ aggout) {
  int sub = threadIdx.x >> 4;
  int fq  = threadIdx.x & 15;
  int node = blockIdx.x * 16 + sub;

  float4 e0 = make_float4(0.f, 0.f, 0.f, 0.f);
  float4 e1 = make_float4(0.f, 0.f, 0.f, 0.f);
  float4 o0 = make_float4(0.f, 0.f, 0.f, 0.f);
  float4 o1 = make_float4(0.f, 0.f, 0.f, 0.f);
  int s = offs[node], e = offs[node + 1];

  const uint4* __restrict__ fb = (const uint4*)feat;   // 16 uint4 per row
  const uint4* __restrict__ zb = (const uint4*)zrow;   // 256 B of zero bits

  int p = s;
  for (; p + 8 <= e; p += 8) {
    const uint4* rp[8];
#pragma unroll
    for (int u = 0; u < 8; ++u)
      rp[u] = fb + (size_t)srcidx[p + u] * 16;
    uint4 w[8];
#pragma unroll
    for (int u = 0; u < 8; ++u) w[u] = rp[u][fq];
#pragma unroll
    for (int u = 0; u < 8; ++u) {
      float4& A = (u & 1) ? o0 : e0;
      float4& B = (u & 1) ? o1 : e1;
      A.x += __uint_as_float(w[u].x << 16);
      A.y += __uint_as_float(w[u].x & 0xffff0000u);
      A.z += __uint_as_float(w[u].y << 16);
      A.w += __uint_as_float(w[u].y & 0xffff0000u);
      B.x += __uint_as_float(w[u].z << 16);
      B.y += __uint_as_float(w[u].z & 0xffff0000u);
      B.z += __uint_as_float(w[u].w << 16);
      B.w += __uint_as_float(w[u].w & 0xffff0000u);
    }
  }
  if (p < e) {
    const uint4* rp[8];
#pragma unroll
    for (int u = 0; u < 8; ++u) {
      int iu = srcidx[p + u];
      rp[u] = (p + u < e) ? (fb + (size_t)iu * 16) : zb;
    }
    uint4 w[8];
#pragma unroll
    for (int u = 0; u < 8; ++u) w[u] = rp[u][fq];
#pragma unroll
    for (int u = 0; u < 8; ++u) {
      float4& A = (u & 1) ? o0 : e0;
      float4& B = (u & 1) ? o1 : e1;
      A.x += __uint_as_float(w[u].x << 16);
      A.y += __uint_as_float(w[u].x & 0xffff0000u);
      A.z += __uint_as_float(w[u].y << 16);
      A.w += __uint_as_float(w[u].y & 0xffff0000u);
      B.x += __uint_as_float(w[u].z << 16);
      B.y += __uint_as_float(w[u].z & 0xffff0000u);
      B.z += __uint_as_float(w[u].w << 16);
      B.w += __uint_as_float(w[u].w & 0xffff0000u);
    }
  }
  float f0 = e0.x + o0.x, f1 = e0.y + o0.y, f2 = e0.z + o0.z, f3 = e0.w + o0.w;
  float f4 = e1.x + o1.x, f5 = e1.y + o1.y, f6 = e1.z + o1.z, f7 = e1.w + o1.w;
  uint4 o;
  o.x = bfr(f0) | (bfr(f1) << 16);
  o.y = bfr(f2) | (bfr(f3) << 16);
  o.z = bfr(f4) | (bfr(f5) << 16);
  o.w = bfr(f6) | (bfr(f7) << 16);
  ((uint4*)aggout)[(size_t)node * 16 + fq] = o;
}

// ---------------- GEMM (bf16 MFMA): out = relu([agg|root]@[Wt^T] + b) -------
// Round-6 structure: A-frags direct global->reg; W staged to LDS in two
// halves; 4 barriers. Epilogue: layer 1 (hout_bf) writes bf16 h1;
// layer 2 (hout_bf==nullptr) fuses pooling from registers: per wave per
// 16-node group, reduce r locally + shfl_xor across hi, one atomic pair per
// (graph,col). Fast path when the 16 rows share one graph (~99%).
__global__ __launch_bounds__(256, 2) void gemm_kernel(
    const unsigned short* __restrict__ aggbf,
    const unsigned short* __restrict__ rootbf,
    const int* __restrict__ hidx,
    const unsigned short* __restrict__ wt,      // [128 c][256 k] bf16
    const float* __restrict__ bias,
    const int* __restrict__ batch,              // layer-2 only
    float* __restrict__ pool,                   // layer-2 only
    unsigned short* __restrict__ hout_bf) {     // layer-1 output
  __shared__ unsigned short B_s[128 * BPITCH];  // 34.8 KB
  int tid = threadIdx.x;
  int nodeBase = blockIdx.x * 128;
  int lane = tid & 63;
  int wv = tid >> 6;
  int wbase = wv * 32;
  int lo = lane & 15, hi = lane >> 4;

  int gnode[2], hroot[2];
#pragma unroll
  for (int mt = 0; mt < 2; ++mt) {
    int g = nodeBase + wbase + mt * 16 + lo;
    if (g > N_NODES - 1) g = N_NODES - 1;
    gnode[mt] = g;
    hroot[mt] = hidx ? hidx[g] : g;
  }

  frag_u afr[2][8];
#pragma unroll
  for (int mt = 0; mt < 2; ++mt) {
#pragma unroll
    for (int t = 0; t < 4; ++t)
      afr[mt][t].u =
          *(const uint4*)(aggbf + (size_t)gnode[mt] * FDIM + t * 32 + hi * 8);
#pragma unroll
    for (int t = 0; t < 4; ++t)
      afr[mt][4 + t].u =
          *(const uint4*)(rootbf + (size_t)hroot[mt] * FDIM + t * 32 + hi * 8);
  }

  f32x4 acc[2][8];
#pragma unroll
  for (int nt = 0; nt < 8; ++nt) {
    float b = bias[nt * 16 + lo];
#pragma unroll
    for (int mt = 0; mt < 2; ++mt) {
      acc[mt][nt][0] = b; acc[mt][nt][1] = b;
      acc[mt][nt][2] = b; acc[mt][nt][3] = b;
    }
  }

  int sr = tid >> 1;                 // B_s row (wt col), 0..127
  int so = (tid & 1) * 64;           // bf16 offset within 128-chunk

#pragma unroll
  for (int h = 0; h < 2; ++h) {      // k-half: h*128 .. h*128+127
    __syncthreads();
#pragma unroll
    for (int i = 0; i < 8; ++i)
      *(uint4*)(B_s + sr * BPITCH + so + i * 8) =
          *(const uint4*)(wt + sr * 256 + h * 128 + so + i * 8);
    __syncthreads();
#pragma unroll
    for (int tt = 0; tt < 4; ++tt) { // k-step of 32 within half
      frag_u bfv[8];
#pragma unroll
      for (int nt = 0; nt < 8; ++nt)
        bfv[nt].u =
            *(const uint4*)&B_s[(nt * 16 + lo) * BPITCH + tt * 32 + hi * 8];
#pragma unroll
      for (int mt = 0; mt < 2; ++mt)
#pragma unroll
        for (int nt = 0; nt < 8; ++nt)
          acc[mt][nt] = __builtin_amdgcn_mfma_f32_16x16x32_bf16(
              afr[mt][h * 4 + tt].b, bfv[nt].b, acc[mt][nt], 0, 0, 0);
    }
  }

  if (hout_bf) {
    // ---- layer 1: bf16 h1 write (D row = hi*4 + r, col = nt*16 + lo)
#pragma unroll
    for (int mt = 0; mt < 2; ++mt) {
#pragma unroll
      for (int r = 0; r < 4; ++r) {
        int n = nodeBase + wbase + mt * 16 + hi * 4 + r;
        if (n < N_NODES) {
          unsigned short* o = hout_bf + (size_t)n * FDIM + lo;
#pragma unroll
          for (int nt = 0; nt < 8; ++nt)
            o[nt * 16] = (unsigned short)bfr(fmaxf(acc[mt][nt][r], 0.f));
        }
      }
    }
  } else {
    // ---- layer 2: relu + fused pooling from registers (no h2 materialized)
#pragma unroll
    for (int mt = 0; mt < 2; ++mt)
#pragma unroll
      for (int nt = 0; nt < 8; ++nt)
#pragma unroll
        for (int r = 0; r < 4; ++r)
          acc[mt][nt][r] = fmaxf(acc[mt][nt][r], 0.f);

#pragma unroll
    for (int mt = 0; mt < 2; ++mt) {
      int rowBase = nodeBase + wbase + mt * 16;   // 16 nodes
      int lastRow = rowBase + 15;
      int gF = batch[rowBase < N_NODES ? rowBase : N_NODES - 1];
      int gL = batch[lastRow < N_NODES ? lastRow : N_NODES - 1];
      if (gF == gL && lastRow < N_NODES) {
        // fast path: whole 16-row group in one graph
#pragma unroll
        for (int nt = 0; nt < 8; ++nt) {
          float mx = fmaxf(fmaxf(acc[mt][nt][0], acc[mt][nt][1]),
                           fmaxf(acc[mt][nt][2], acc[mt][nt][3]));
          float sm = acc[mt][nt][0] + acc[mt][nt][1] +
                     acc[mt][nt][2] + acc[mt][nt][3];
          mx = fmaxf(mx, __shfl_xor(mx, 16));
          sm += __shfl_xor(sm, 16);
          mx = fmaxf(mx, __shfl_xor(mx, 32));
          sm += __shfl_xor(sm, 32);
          if (hi == 0) {
            int c = nt * 16 + lo;
            atomicMax((unsigned int*)&pool[gF * 256 + c], __float_as_uint(mx));
            atomicAdd(&pool[gF * 256 + 128 + c], sm);
          }
        }
      } else {
        // slow path: per-row graph lookup (group straddles boundary / tail)
#pragma unroll
        for (int r = 0; r < 4; ++r) {
          int n = rowBase + hi * 4 + r;
          if (n < N_NODES) {
            int g = batch[n];
#pragma unroll
            for (int nt = 0; nt < 8; ++nt) {
              int c = nt * 16 + lo;
              atomicMax((unsigned int*)&pool[g * 256 + c],
                        __float_as_uint(acc[mt][nt][r]));
              atomicAdd(&pool[g * 256 + 128 + c], acc[mt][nt][r]);
            }
          }
        }
      }
    }
  }
}

__global__ void pool_fin_kernel(float* __restrict__ pool,
                                const int* __restrict__ start) {
  int gid = blockIdx.x * 256 + threadIdx.x;   // 8192
  int g = gid >> 7, f = gid & 127;
  int cnt = start[g + 1] - start[g];
  float c = (float)(cnt > 1 ? cnt : 1);
  pool[g * 256 + 128 + f] /= c;
}

// ---------------- MLP head ----------------
__global__ void head1_kernel(const float* __restrict__ pool,
                             const float* __restrict__ lw1,
                             const float* __restrict__ lb1,
                             float* __restrict__ t1) {
  int gid = blockIdx.x * 256 + threadIdx.x;   // 8192
  int r = gid >> 7, c = gid & 127;
  float acc = lb1[c];
  for (int k = 0; k < 256; ++k) acc += pool[r * 256 + k] * lw1[k * 128 + c];
  t1[gid] = fmaxf(acc, 0.f);
}

__global__ void head2_kernel(const float* __restrict__ t1,
                             const float* __restrict__ lw2,
                             const float* __restrict__ lb2,
                             float* __restrict__ t2) {
  int gid = blockIdx.x * 256 + threadIdx.x;   // 4096
  int r = gid >> 6, c = gid & 63;
  float acc = lb2[c];
  for (int k = 0; k < 128; ++k) acc += t1[r * 128 + k] * lw2[k * 64 + c];
  t2[gid] = fmaxf(acc, 0.f);
}

__global__ __launch_bounds__(256) void head3_kernel(
    const float* __restrict__ t2, const float* __restrict__ lw3,
    const float* __restrict__ lb3, float* __restrict__ out) {
  __shared__ float lg[N_GRAPHS * N_LABELS];
  __shared__ float col[N_LABELS];
  int tid = threadIdx.x;
  for (int o = tid; o < N_GRAPHS * N_LABELS; o += 256) {
    int r = o / N_LABELS, c = o - r * N_LABELS;
    float acc = lb3[c];
    for (int k = 0; k < 64; ++k) acc += t2[r * 64 + k] * lw3[k * N_LABELS + c];
    lg[o] = acc;
  }
  __syncthreads();
  if (tid < N_LABELS) {
    float m = -1e30f;
    for (int r = 0; r < N_GRAPHS; ++r) m = fmaxf(m, lg[r * N_LABELS + tid]);
    float s = 0.f;
    for (int r = 0; r < N_GRAPHS; ++r) s += expf(lg[r * N_LABELS + tid] - m);
    col[tid] = m + logf(s);
  }
  __syncthreads();
  for (int o = tid; o < N_GRAPHS * N_LABELS; o += 256) {
    int c = o % N_LABELS;
    out[o] = lg[o] - col[c];
  }
}

// ---------------- launch ----------------
extern "C" void kernel_launch(void* const* d_in, const int* in_sizes, int n_in,
                              void* d_out, int out_size, void* d_ws, size_t ws_size,
                              hipStream_t stream) {
  const int*   x     = (const int*)  d_in[0];
  const int*   ei    = (const int*)  d_in[1];
  const int*   batch = (const int*)  d_in[2];
  const float* emb   = (const float*)d_in[3];
  const float* w1rel = (const float*)d_in[4];
  const float* w1rt  = (const float*)d_in[5];
  const float* b1    = (const float*)d_in[6];
  const float* w2rel = (const float*)d_in[7];
  const float* w2rt  = (const float*)d_in[8];
  const float* b2    = (const float*)d_in[9];
  const float* lw1   = (const float*)d_in[10];
  const float* lb1   = (const float*)d_in[11];
  const float* lw2   = (const float*)d_in[12];
  const float* lb2   = (const float*)d_in[13];
  const float* lw3   = (const float*)d_in[14];
  const float* lb3   = (const float*)d_in[15];
  float* out = (float*)d_out;

  char* ws = (char*)d_ws;
  const size_t HB   = 51200000;    // N_NODES*FDIM*4
  const size_t CSRB = 6400128;     // (N_EDGES+32) ints
  const size_t OFFB = 400128;      // (N_NODES+1) ints, rounded
  // embbf aliases [0,12.8MB)
  unsigned short* embbf = (unsigned short*)(ws);
  // scan buffers alias [13MB,20.1MB)
  int*   cntmat  = (int*)  (ws + 13000000);   // SCAN_M ints = 3.2MB
  int*   S       = (int*)  (ws + 16500000);   // SCAN_M ints = 3.2MB
  int*   bsum    = (int*)  (ws + 20000000);   // SB1_BLOCKS ints = 12.5KB
  // aggbf (25.6 MB used) aliases ebuf region
  unsigned short* aggbf = (unsigned short*)(ws + HB);
  int*   ebuf    = (int*)  (ws + HB);
  int*   csr     = (int*)  (ws + 2 * HB);
  int*   csr2    = (int*)  (ws + 2 * HB + CSRB);
  int*   offsets = (int*)  (ws + 2 * HB + 2 * CSRB);
  int*   bstart  = (int*)  (ws + 2 * HB + 2 * CSRB + OFFB);            // 6,400
  float* zrow    = (float*)(ws + 2 * HB + 2 * CSRB + OFFB + 6400);     // 512
  int*   start   = (int*)  (ws + 2 * HB + 2 * CSRB + OFFB + 6912);     // 512
  float* pool    = (float*)(ws + 2 * HB + 2 * CSRB + OFFB + 7424);     // 65,536
  float* t1      = (float*)(ws + 2 * HB + 2 * CSRB + OFFB + 72960);    // 32,768
  float* t2      = (float*)(ws + 2 * HB + 2 * CSRB + OFFB + 105728);   // 16,384
  unsigned short* hbf =
      (unsigned short*)(ws + 2 * HB + 2 * CSRB + OFFB + 122112);       // 25.6 MB
  unsigned short* wt1 =
      (unsigned short*)(ws + 2 * HB + 2 * CSRB + OFFB + 122112 + 25600000);
  unsigned short* wt2 = wt1 + 128 * 256;

  prep_kernel<<<6961, 256, 0, stream>>>(emb, embbf, w1rel, w1rt, w2rel, w2rt,
                                        wt1, wt2, batch, start, pool, zrow,
                                        csr, csr2, offsets);

  histA_kernel<<<NCHUNKS, 256, 0, stream>>>(ei, cntmat);
  scanB1_kernel<<<SB1_BLOCKS, 256, 0, stream>>>(cntmat, S, bsum);
  scanB2_kernel<<<1, 512, 0, stream>>>(bsum);
  scanB3_kernel<<<SB1_BLOCKS, 256, 0, stream>>>(S, bsum, bstart);
  scatA_kernel<<<NCHUNKS, 256, 0, stream>>>(ei, S, ebuf);
  fill2_kernel<<<P_BKT, 256, 0, stream>>>(ebuf, bstart, x, offsets, csr, csr2);

  // layer 1: agg over bf16 emb rows (csr2 = x[src]); root = embbf via x
  agg_kernel<<<N_NODES / 16, 256, 0, stream>>>(embbf, csr2, offsets, zrow, aggbf);
  gemm_kernel<<<(N_NODES + 127) / 128, 256, 0, stream>>>(
      aggbf, embbf, x, wt1, b1, (const int*)nullptr, (float*)nullptr, hbf);

  // layer 2: agg over bf16 h1 rows (csr); root = hbf; pooling fused
  agg_kernel<<<N_NODES / 16, 256, 0, stream>>>(hbf, csr, offsets, zrow, aggbf);
  gemm_kernel<<<(N_NODES + 127) / 128, 256, 0, stream>>>(
      aggbf, hbf, (const int*)nullptr, wt2, b2, batch, pool,
      (unsigned short*)nullptr);

  pool_fin_kernel<<<32, 256, 0, stream>>>(pool, start);

  head1_kernel<<<32, 256, 0, stream>>>(pool, lw1, lb1, t1);
  head2_kernel<<<16, 256, 0, stream>>>(t1, lw2, lb2, t2);
  head3_kernel<<<1, 256, 0, stream>>>(t2, lw3, lb3, out);
}